// Round 1
// 309.705 us; speedup vs baseline: 1.0824x; 1.0824x over previous
//
#include <hip/hip_runtime.h>

// YOLO loss on MI355X. Layout:
//   prediction: (N, S, S, 90)  fp32, N=8192, S=7  -> 401408 cells x 90 ch
//   target:     (N, S, S, 85)  fp32               -> 401408 cells x 85 ch
// Output: 6 fp32 scalars.
//
// R5: R4 was latency-serialized (VALUBusy 4.5%, occ 23%, eff. BW ~2 TB/s of a
// 6.3 TB/s ceiling). Cause: depth-0 staging -- per tile, global_load_lds then
// __syncthreads(), which the compiler lowers as s_waitcnt vmcnt(0) before
// s_barrier, exposing a full memory round trip per tile with only 3
// phase-locked blocks/CU to cover it.
// Fix (T3/T4): double-buffered LDS, counted vmcnt, raw s_barrier:
//   - tile = 32 cells -> buffer 22.4 KB; 2 buffers = 44.8 KB keeps 3 blocks/CU
//   - staging is wave-uniform: each of the 4 waves issues exactly 6
//     global_load_lds dwordx4 per tile (350 contiguous 16B chunks/wave), so
//     `s_waitcnt vmcnt(6)` after issuing tile t+1's loads == "tile t ready"
//   - never vmcnt(0) inside the loop; raw __builtin_amdgcn_s_barrier() does
//     NOT emit the drain (m201 8-phase template pattern)
//   - atomics spread across 8 replicas x 5 counters, one 128B line each
//     (same-line atomics from 1568 blocks across 8 XCDs serialize at one L2
//     bank); compact fallback if ws_size is small.

#define NCELLS (8192 * 49)                 // 401408
#define TILE_CELLS 32
#define NTILES (NCELLS / TILE_CELLS)       // 12544
#define TPB 8                              // tiles per block
#define NBLOCKS (NTILES / TPB)             // 1568
#define T_FLOATS (TILE_CELLS * 85)         // 2720 floats of target per tile
#define P_FLOATS (TILE_CELLS * 90)         // 2880 floats of pred per tile
#define BUF_FLOATS (T_FLOATS + P_FLOATS)   // 5600 floats = 22400 B per buffer
#define T_CHUNKS (T_FLOATS / 4)            // 680 16B chunks (target region)
#define TOT_CHUNKS (BUF_FLOATS / 4)        // 1400 chunks per tile
#define W_CHUNKS (TOT_CHUNKS / 4)          // 350 chunks per wave

constexpr float BSF = 8192.0f;

__device__ __forceinline__ void g2lds16(const float* g, float* s) {
    __builtin_amdgcn_global_load_lds(
        (const __attribute__((address_space(1))) void*)g,
        (__attribute__((address_space(3))) void*)s,
        16, 0, 0);
}

__device__ __forceinline__ void rel2abs(float x, float y, float w, float h,
                                        float fi, float fj,
                                        float& x1, float& y1, float& x2, float& y2) {
    float xc = (x + fj) / 7.0f;
    float yc = (y + fi) / 7.0f;
    float hw = w * 0.5f, hh = h * 0.5f;
    x1 = xc - hw; y1 = yc - hh; x2 = xc + hw; y2 = yc + hh;
}

__device__ __forceinline__ float iou_abs(float ax1, float ay1, float ax2, float ay2,
                                         float bx1, float by1, float bx2, float by2) {
    float iw = fminf(ax2, bx2) - fmaxf(ax1, bx1); iw = fmaxf(iw, 0.0f);
    float ih = fminf(ay2, by2) - fmaxf(ay1, by1); ih = fmaxf(ih, 0.0f);
    float inter  = iw * ih;
    float area_a = (ax2 - ax1) * (ay2 - ay1);
    float area_b = (bx2 - bx1) * (by2 - by1);
    return inter / (area_a + area_b - inter + 1e-6f);
}

// Stage one 32-cell tile into an LDS buffer. Flat layout:
//   buf[0 .. 2720)        = target rows (85 floats/cell)
//   buf[2720 .. 5600)     = pred rows   (90 floats/cell)
// Wave w owns chunks [350w, 350(w+1)): 5 full 64-lane loads + 1 partial
// (30 active lanes) -> every wave issues EXACTLY 6 global_load_lds, so
// vmcnt accounting is wave-uniform. LDS dest = base + 16*chunk = wave-uniform
// base + lane*16 (DMA constraint satisfied). Global src is per-lane (the
// chunk that straddles the tgt/pred boundary selects per lane).
__device__ __forceinline__ void stage_tile(const float* __restrict__ pred,
                                           const float* __restrict__ tgt,
                                           float* lbuf, int tile,
                                           int wid, int lane) {
    const float* tg = tgt  + (size_t)tile * T_FLOATS;
    const float* pg = pred + (size_t)tile * P_FLOATS;
    #pragma unroll
    for (int i = 0; i < 5; ++i) {
        const int q = W_CHUNKS * wid + 64 * i + lane;
        const float* src = (q < T_CHUNKS) ? (tg + 4 * q) : (pg + 4 * (q - T_CHUNKS));
        g2lds16(src, lbuf + 4 * q);
    }
    {   // tail: lanes 0..29 of EVERY wave -> instruction still issues per wave
        const int cw = 320 + lane;
        if (cw < W_CHUNKS) {
            const int q = W_CHUNKS * wid + cw;
            const float* src = (q < T_CHUNKS) ? (tg + 4 * q) : (pg + 4 * (q - T_CHUNKS));
            g2lds16(src, lbuf + 4 * q);
        }
    }
}

__global__ __launch_bounds__(256) void yolo_main(const float* __restrict__ pred,
                                                 const float* __restrict__ tgt,
                                                 float* __restrict__ acc,
                                                 int nrep, int sstride) {
    __shared__ __align__(16) float lds[2][BUF_FLOATS];   // 2 x 22400 B
    __shared__ float smr[4 * 5];

    const int tid  = threadIdx.x;
    const int lane = tid & 63;
    const int wid  = tid >> 6;

    float a_xy = 0.f, a_wh = 0.f, a_co = 0.f, a_cn = 0.f, a_cl = 0.f;

    const int tile0 = blockIdx.x * TPB;

    // prologue: prefetch tile 0
    stage_tile(pred, tgt, &lds[0][0], tile0, wid, lane);

    for (int it = 0; it < TPB; ++it) {
        if (it + 1 < TPB) {
            // issue next tile's 6 loads FIRST, then wait for current tile's 6
            stage_tile(pred, tgt, &lds[(it + 1) & 1][0], tile0 + it + 1, wid, lane);
            asm volatile("s_waitcnt vmcnt(6)" ::: "memory");
        } else {
            asm volatile("s_waitcnt vmcnt(0)" ::: "memory");
        }
        __builtin_amdgcn_s_barrier();          // all waves' tile-it DMA landed
        asm volatile("" ::: "memory");         // no LDS read hoists above this

        // ---------- compute tile it ----------
        {
            const float* buf  = &lds[it & 1][0];
            const int   cell  = lane & 31;     // cell within tile
            const int   half  = lane >> 5;     // 0/1: which 10-channel slice
            const float* tb   = buf + 85 * cell;
            const float* pb   = buf + T_FLOATS + 90 * cell;

            const float objf = (tb[4] != 0.0f) ? 1.0f : 0.0f;

            // class SSE: wave w, half h covers channels [20w+10h, 20w+10h+10)
            const int c0 = 20 * wid + 10 * half;
            float s = 0.f;
            #pragma unroll
            for (int k = 0; k < 10; ++k) {
                float d = tb[5 + c0 + k] - pb[10 + c0 + k];
                s = fmaf(d, d, s);
            }
            a_cl += objf * s;

            // box + conf: rotate across waves per tile; lanes 0..31 = cells
            if (half == 0 && wid == (it & 3)) {
                float tx = tb[0], ty = tb[1], tw = tb[2], th = tb[3], tc = tb[4];
                float p0x = pb[0], p0y = pb[1], p0w = pb[2], p0h = pb[3];
                float p1x = pb[5], p1y = pb[6], p1w = pb[7], p1h = pb[8];
                float pc  = pb[9];                 // pred_c = prediction[..., 9]

                int gcell = (tile0 + it) * TILE_CELLS + cell;
                int sij   = gcell % 49;
                float fi  = (float)(sij / 7);
                float fj  = (float)(sij % 7);

                float t1, t2, t3, t4, a1, a2, a3, a4, b1, b2, b3, b4;
                rel2abs(tx,  ty,  tw,  th,  fi, fj, t1, t2, t3, t4);
                rel2abs(p0x, p0y, p0w, p0h, fi, fj, a1, a2, a3, a4);
                rel2abs(p1x, p1y, p1w, p1h, fi, fj, b1, b2, b3, b4);

                float iou0 = iou_abs(t1, t2, t3, t4, a1, a2, a3, a4);
                float iou1 = iou_abs(t1, t2, t3, t4, b1, b2, b3, b4);

                bool sel = iou0 > iou1;   // ref: where(iou0>iou1, pred[5:10], pred[0:5])
                float xh = sel ? p1x : p0x;
                float yh = sel ? p1y : p0y;
                float wh = sel ? p1w : p0w;
                float hh = sel ? p1h : p0h;

                float obx = (tc != 0.0f) ? 1.0f : 0.0f;

                float dx = tx - xh, dy = ty - yh;
                a_xy += obx * (dx * dx + dy * dy);

                float sw = sqrtf(tw) - sqrtf(fmaxf(wh, 0.0f));
                float sh = sqrtf(th) - sqrtf(fmaxf(hh, 0.0f));
                a_wh += obx * (sw * sw + sh * sh);

                float ce = tc - pc; ce *= ce;
                a_co += obx * ce;
                a_cn += (1.0f - obx) * ce;
            }
        }

        asm volatile("" ::: "memory");         // compute reads stay above barrier
        __builtin_amdgcn_s_barrier();          // buf[it&1] safe to overwrite next iter
    }

    // ---------- reduce: wave shfl -> LDS -> spread atomics ----------
    #pragma unroll
    for (int off = 32; off; off >>= 1) {
        a_xy += __shfl_down(a_xy, off, 64);
        a_wh += __shfl_down(a_wh, off, 64);
        a_co += __shfl_down(a_co, off, 64);
        a_cn += __shfl_down(a_cn, off, 64);
        a_cl += __shfl_down(a_cl, off, 64);
    }
    if (lane == 0) {
        smr[wid * 5 + 0] = a_xy; smr[wid * 5 + 1] = a_wh; smr[wid * 5 + 2] = a_co;
        smr[wid * 5 + 3] = a_cn; smr[wid * 5 + 4] = a_cl;
    }
    __syncthreads();
    if (tid == 0) {
        float s0 = 0.f, s1 = 0.f, s2 = 0.f, s3 = 0.f, s4 = 0.f;
        #pragma unroll
        for (int w = 0; w < 4; ++w) {
            s0 += smr[w * 5 + 0]; s1 += smr[w * 5 + 1]; s2 += smr[w * 5 + 2];
            s3 += smr[w * 5 + 3]; s4 += smr[w * 5 + 4];
        }
        const int rep = (int)(blockIdx.x & (unsigned)(nrep - 1));
        float* a0 = acc + (size_t)rep * 5 * sstride;
        atomicAdd(&a0[0 * sstride], s0);
        atomicAdd(&a0[1 * sstride], s1);
        atomicAdd(&a0[2 * sstride], s2);
        atomicAdd(&a0[3 * sstride], s3);
        atomicAdd(&a0[4 * sstride], s4);
    }
}

__global__ void yolo_finalize(const float* __restrict__ acc, float* __restrict__ out,
                              int nrep, int sstride) {
    if (threadIdx.x == 0 && blockIdx.x == 0) {
        float s[5] = {0.f, 0.f, 0.f, 0.f, 0.f};
        for (int r = 0; r < nrep; ++r)
            for (int k = 0; k < 5; ++k)
                s[k] += acc[((size_t)r * 5 + k) * sstride];
        float lxy = s[0] / BSF;
        float lwh = s[1] / BSF;
        float lco = s[2] / BSF;
        float lcn = s[3] / BSF;
        float lcl = s[4] / BSF;
        out[0] = (5.0f * lxy + 5.0f * lwh + lco + 0.5f * lcn + lcl) / BSF;
        out[1] = lxy;
        out[2] = lwh;
        out[3] = lco;
        out[4] = lcn;
        out[5] = lcl;
    }
}

extern "C" void kernel_launch(void* const* d_in, const int* in_sizes, int n_in,
                              void* d_out, int out_size, void* d_ws, size_t ws_size,
                              hipStream_t stream) {
    const float* pred = (const float*)d_in[0];
    const float* tgt  = (const float*)d_in[1];
    float* out = (float*)d_out;
    float* acc = (float*)d_ws;

    // 8 replicas x 5 counters, one 128B line per counter slot (stride 32
    // floats) -> 5120 B. Fall back to the compact 20 B layout if ws is tiny.
    int nrep, sstride; size_t zbytes;
    if (ws_size >= 8 * 5 * 32 * sizeof(float)) { nrep = 8; sstride = 32; zbytes = 8 * 5 * 32 * sizeof(float); }
    else                                       { nrep = 1; sstride = 1;  zbytes = 5 * sizeof(float); }

    // d_ws is poisoned (0xAA) before every timed launch -> must zero here.
    hipMemsetAsync(acc, 0, zbytes, stream);

    yolo_main<<<NBLOCKS, 256, 0, stream>>>(pred, tgt, acc, nrep, sstride);
    yolo_finalize<<<1, 64, 0, stream>>>(acc, out, nrep, sstride);
}

// Round 2
// 300.489 us; speedup vs baseline: 1.1156x; 1.0307x over previous
//
#include <hip/hip_runtime.h>

// YOLO loss on MI355X. Layout:
//   prediction: (N, S, S, 90)  fp32, N=8192, S=7  -> 401408 cells x 90 ch
//   target:     (N, S, S, 85)  fp32               -> 401408 cells x 85 ch
// Output: 6 fp32 scalars.
//
// R6: R5 (block-lockstep double-buffer, counted vmcnt) reached only 2.4 TB/s
// effective (118 us) with VALUBusy 9.4% -- still latency-bound. The two
// s_barriers per tile couple 4 waves: the block advances at the slowest
// wave's memory-completion each tile, and in-flight bytes collapse at every
// rendezvous.
// Fix: WAVE-PRIVATE barrier-free pipeline.
//   - each wave owns an 8-cell tile stream + private 2 x 5.6 KB LDS slice
//   - 6 global_load_lds dwordx4 per tile (tgt 170 chunks: 64+64+42,
//     pred 180 chunks: 64+64+52), contiguous runs -> SGPR base + imm offsets,
//     no per-lane select
//   - per-wave counted vmcnt(6); NO s_barrier anywhere in the loop
//   - buffer-reuse hazard fenced per-wave by s_waitcnt lgkmcnt(0) ("memory"
//     clobber keeps ds_reads from sinking past the overwriting DMA)
//   - compute: 8 lanes/cell x 10 class channels = 80 exactly; part==0 lanes
//     do box/conf for their cell
//   - 12 free-running waves/CU, each 6-12 loads outstanding continuously
// LDS: 4 waves x 2 bufs x 5600 B = 44.8 KB -> 3 blocks/CU.
// Grid: 3136 blocks x 4 waves x 4 tiles x 8 cells = 401408 cells exactly.

#define NCELLS (8192 * 49)                  // 401408
#define CPT 8                               // cells per wave-tile
#define TPW 4                               // tiles per wave
#define WPB 4                               // waves per block
#define CELLS_PER_BLOCK (CPT * TPW * WPB)   // 128
#define NBLOCKS (NCELLS / CELLS_PER_BLOCK)  // 3136
#define TFL (CPT * 85)                      // 680 floats of tgt per tile
#define PFL (CPT * 90)                      // 720 floats of pred per tile
#define BUF_FL (TFL + PFL)                  // 1400 floats = 5600 B per buffer

constexpr float BSF = 8192.0f;

__device__ __forceinline__ void g2lds16(const float* g, float* s) {
    __builtin_amdgcn_global_load_lds(
        (const __attribute__((address_space(1))) void*)g,
        (__attribute__((address_space(3))) void*)s,
        16, 0, 0);
}

__device__ __forceinline__ void rel2abs(float x, float y, float w, float h,
                                        float fi, float fj,
                                        float& x1, float& y1, float& x2, float& y2) {
    float xc = (x + fj) / 7.0f;
    float yc = (y + fi) / 7.0f;
    float hw = w * 0.5f, hh = h * 0.5f;
    x1 = xc - hw; y1 = yc - hh; x2 = xc + hw; y2 = yc + hh;
}

__device__ __forceinline__ float iou_abs(float ax1, float ay1, float ax2, float ay2,
                                         float bx1, float by1, float bx2, float by2) {
    float iw = fminf(ax2, bx2) - fmaxf(ax1, bx1); iw = fmaxf(iw, 0.0f);
    float ih = fminf(ay2, by2) - fmaxf(ay1, by1); ih = fmaxf(ih, 0.0f);
    float inter  = iw * ih;
    float area_a = (ax2 - ax1) * (ay2 - ay1);
    float area_b = (bx2 - bx1) * (by2 - by1);
    return inter / (area_a + area_b - inter + 1e-6f);
}

// Stage one 8-cell tile into this wave's LDS buffer. Layout:
//   wbuf[0 .. 680)    = 8 target rows (85 floats each)
//   wbuf[680 .. 1400) = 8 pred rows   (90 floats each)
// Exactly 6 global_load_lds per wave (partial-exec tails still issue ->
// vmcnt accounting is wave-uniform at 6/tile). LDS dest = wave-uniform
// base + lane*16 for every load (DMA constraint). Sources are contiguous
// runs: SGPR base + immediate offsets, no per-lane select.
__device__ __forceinline__ void stage_tile(const float* __restrict__ tg,
                                           const float* __restrict__ pg,
                                           float* wbuf, int lane) {
    g2lds16(tg + 4 * lane,         wbuf + 4 * lane);
    g2lds16(tg + 4 * (64 + lane),  wbuf + 4 * (64 + lane));
    if (lane < 42)
        g2lds16(tg + 4 * (128 + lane), wbuf + 4 * (128 + lane));
    g2lds16(pg + 4 * lane,         wbuf + TFL + 4 * lane);
    g2lds16(pg + 4 * (64 + lane),  wbuf + TFL + 4 * (64 + lane));
    if (lane < 52)
        g2lds16(pg + 4 * (128 + lane), wbuf + TFL + 4 * (128 + lane));
}

__global__ __launch_bounds__(256) void yolo_main(const float* __restrict__ pred,
                                                 const float* __restrict__ tgt,
                                                 float* __restrict__ acc,
                                                 int nrep, int sstride) {
    __shared__ __align__(16) float lds[WPB][2][BUF_FL];   // 44.8 KB
    __shared__ float smr[WPB * 5];

    const int tid  = threadIdx.x;
    const int lane = tid & 63;
    const int wid  = tid >> 6;

    float* const wb0 = &lds[wid][0][0];
    float* const wb1 = &lds[wid][1][0];

    const int wave_id = blockIdx.x * WPB + wid;
    const int tile0   = wave_id * TPW;

    float a_xy = 0.f, a_wh = 0.f, a_co = 0.f, a_cn = 0.f, a_cl = 0.f;

    const int cell = lane >> 3;        // 0..7: cell within tile
    const int part = lane & 7;         // 0..7: 10-channel class slice
    const int c0   = 10 * part;

    // prologue: prefetch tile 0 into buffer 0
    stage_tile(tgt + (size_t)tile0 * TFL, pred + (size_t)tile0 * PFL, wb0, lane);

    #pragma unroll
    for (int k = 0; k < TPW; ++k) {
        float* const cur = (k & 1) ? wb1 : wb0;
        float* const nxt = (k & 1) ? wb0 : wb1;

        if (k + 1 < TPW) {
            // per-wave fence: all my ds_reads of `nxt` (from tile k-1) retired
            asm volatile("s_waitcnt lgkmcnt(0)" ::: "memory");
            const int t = tile0 + k + 1;
            stage_tile(tgt + (size_t)t * TFL, pred + (size_t)t * PFL, nxt, lane);
            asm volatile("s_waitcnt vmcnt(6)" ::: "memory");   // tile k landed
        } else {
            asm volatile("s_waitcnt vmcnt(0)" ::: "memory");
        }

        // ---------- compute tile k (wave-private, no barrier) ----------
        const float* tb = cur + 85 * cell;
        const float* pb = cur + TFL + 90 * cell;

        const float objf = (tb[4] != 0.0f) ? 1.0f : 0.0f;

        float s = 0.f;
        #pragma unroll
        for (int c = 0; c < 10; ++c) {
            float d = tb[5 + c0 + c] - pb[10 + c0 + c];
            s = fmaf(d, d, s);
        }
        a_cl += objf * s;

        if (part == 0) {
            float tx = tb[0], ty = tb[1], tw = tb[2], th = tb[3], tc = tb[4];
            float p0x = pb[0], p0y = pb[1], p0w = pb[2], p0h = pb[3];
            float p1x = pb[5], p1y = pb[6], p1w = pb[7], p1h = pb[8];
            float pc  = pb[9];                 // pred_c = prediction[..., 9]

            int gcell = (tile0 + k) * CPT + cell;
            int sij   = gcell % 49;
            float fi  = (float)(sij / 7);
            float fj  = (float)(sij % 7);

            float t1, t2, t3, t4, a1, a2, a3, a4, b1, b2, b3, b4;
            rel2abs(tx,  ty,  tw,  th,  fi, fj, t1, t2, t3, t4);
            rel2abs(p0x, p0y, p0w, p0h, fi, fj, a1, a2, a3, a4);
            rel2abs(p1x, p1y, p1w, p1h, fi, fj, b1, b2, b3, b4);

            float iou0 = iou_abs(t1, t2, t3, t4, a1, a2, a3, a4);
            float iou1 = iou_abs(t1, t2, t3, t4, b1, b2, b3, b4);

            bool sel = iou0 > iou1;   // ref: where(iou0>iou1, pred[5:10], pred[0:5])
            float xh = sel ? p1x : p0x;
            float yh = sel ? p1y : p0y;
            float wh = sel ? p1w : p0w;
            float hh = sel ? p1h : p0h;

            float dx = tx - xh, dy = ty - yh;
            a_xy += objf * (dx * dx + dy * dy);

            float sw = sqrtf(tw) - sqrtf(fmaxf(wh, 0.0f));
            float sh = sqrtf(th) - sqrtf(fmaxf(hh, 0.0f));
            a_wh += objf * (sw * sw + sh * sh);

            float ce = tc - pc; ce *= ce;
            a_co += objf * ce;
            a_cn += (1.0f - objf) * ce;
        }
    }

    // ---------- reduce: wave shfl -> LDS -> spread atomics ----------
    #pragma unroll
    for (int off = 32; off; off >>= 1) {
        a_xy += __shfl_down(a_xy, off, 64);
        a_wh += __shfl_down(a_wh, off, 64);
        a_co += __shfl_down(a_co, off, 64);
        a_cn += __shfl_down(a_cn, off, 64);
        a_cl += __shfl_down(a_cl, off, 64);
    }
    if (lane == 0) {
        smr[wid * 5 + 0] = a_xy; smr[wid * 5 + 1] = a_wh; smr[wid * 5 + 2] = a_co;
        smr[wid * 5 + 3] = a_cn; smr[wid * 5 + 4] = a_cl;
    }
    __syncthreads();   // the ONLY block-wide sync
    if (tid == 0) {
        float s0 = 0.f, s1 = 0.f, s2 = 0.f, s3 = 0.f, s4 = 0.f;
        #pragma unroll
        for (int w = 0; w < 4; ++w) {
            s0 += smr[w * 5 + 0]; s1 += smr[w * 5 + 1]; s2 += smr[w * 5 + 2];
            s3 += smr[w * 5 + 3]; s4 += smr[w * 5 + 4];
        }
        const int rep = (int)(blockIdx.x & (unsigned)(nrep - 1));
        float* a0 = acc + (size_t)rep * 5 * sstride;
        atomicAdd(&a0[0 * sstride], s0);
        atomicAdd(&a0[1 * sstride], s1);
        atomicAdd(&a0[2 * sstride], s2);
        atomicAdd(&a0[3 * sstride], s3);
        atomicAdd(&a0[4 * sstride], s4);
    }
}

__global__ void yolo_finalize(const float* __restrict__ acc, float* __restrict__ out,
                              int nrep, int sstride) {
    if (threadIdx.x == 0 && blockIdx.x == 0) {
        float s[5] = {0.f, 0.f, 0.f, 0.f, 0.f};
        for (int r = 0; r < nrep; ++r)
            for (int k = 0; k < 5; ++k)
                s[k] += acc[((size_t)r * 5 + k) * sstride];
        float lxy = s[0] / BSF;
        float lwh = s[1] / BSF;
        float lco = s[2] / BSF;
        float lcn = s[3] / BSF;
        float lcl = s[4] / BSF;
        out[0] = (5.0f * lxy + 5.0f * lwh + lco + 0.5f * lcn + lcl) / BSF;
        out[1] = lxy;
        out[2] = lwh;
        out[3] = lco;
        out[4] = lcn;
        out[5] = lcl;
    }
}

extern "C" void kernel_launch(void* const* d_in, const int* in_sizes, int n_in,
                              void* d_out, int out_size, void* d_ws, size_t ws_size,
                              hipStream_t stream) {
    const float* pred = (const float*)d_in[0];
    const float* tgt  = (const float*)d_in[1];
    float* out = (float*)d_out;
    float* acc = (float*)d_ws;

    // 8 replicas x 5 counters, one 128B line per counter slot (stride 32
    // floats) -> 5120 B. Fall back to the compact 20 B layout if ws is tiny.
    int nrep, sstride; size_t zbytes;
    if (ws_size >= 8 * 5 * 32 * sizeof(float)) { nrep = 8; sstride = 32; zbytes = 8 * 5 * 32 * sizeof(float); }
    else                                       { nrep = 1; sstride = 1;  zbytes = 5 * sizeof(float); }

    // d_ws is poisoned (0xAA) before every timed launch -> must zero here.
    hipMemsetAsync(acc, 0, zbytes, stream);

    yolo_main<<<NBLOCKS, 256, 0, stream>>>(pred, tgt, acc, nrep, sstride);
    yolo_finalize<<<1, 64, 0, stream>>>(acc, out, nrep, sstride);
}